// Round 12
// baseline (144.874 us; speedup 1.0000x reference)
//
#include <hip/hip_runtime.h>
#include <math.h>

#define QTOT 2048

using bf16x8 = __attribute__((ext_vector_type(8))) short;
using f32x4  = __attribute__((ext_vector_type(4))) float;

static __device__ __forceinline__ short f2bf(float f) {
    union { float f; unsigned u; } v; v.f = f;
    unsigned r = v.u + 0x7fffu + ((v.u >> 16) & 1u);
    return (short)(r >> 16);
}
static __device__ __forceinline__ unsigned cvt_pk(float a, float b) {
    unsigned r;
    asm("v_cvt_pk_bf16_f32 %0, %1, %2" : "=v"(r) : "v"(a), "v"(b));
    return r;
}
static __device__ __forceinline__ bf16x8 pack8(float a0, float a1, float a2, float a3,
                                               float a4, float a5, float a6, float a7) {
    union { unsigned u[4]; bf16x8 v; } z;
    z.u[0] = cvt_pk(a0, a1); z.u[1] = cvt_pk(a2, a3);
    z.u[2] = cvt_pk(a4, a5); z.u[3] = cvt_pk(a6, a7);
    return z.v;
}

// ---------------- K1: pack all weights into MFMA B-fragment order ----------
__global__ void wconv(const float* __restrict__ Wq, const float* __restrict__ Wk,
                      const float* __restrict__ Wo, const float* __restrict__ Wv,
                      const float* __restrict__ W1, const float* __restrict__ W2,
                      short* __restrict__ WqP, short* __restrict__ WkP,
                      short* __restrict__ WoP, short* __restrict__ WvP,
                      short* __restrict__ W1P, short* __restrict__ W2P) {
    int b = blockIdx.x, t = threadIdx.x;
    const float* W; short* P; int N, KK, ci; bool tr = false;
    if (b < 32)       { W = Wq; P = WqP; N = 256;  KK = 8;  ci = b * 256 + t; }
    else if (b < 64)  { W = Wk; P = WkP; N = 256;  KK = 8;  ci = (b - 32) * 256 + t; tr = true; }
    else if (b < 96)  { W = Wo; P = WoP; N = 256;  KK = 8;  ci = (b - 64) * 256 + t; }
    else if (b < 128) { W = Wv; P = WvP; N = 256;  KK = 8;  ci = (b - 96) * 256 + t; }
    else if (b < 256) { W = W1; P = W1P; N = 1024; KK = 8;  ci = (b - 128) * 256 + t; }
    else              { W = W2; P = W2P; N = 256;  KK = 32; ci = (b - 256) * 256 + t; }
    int cb = ci / (KK * 64);
    int rem = ci - cb * (KK * 64);
    int kk = rem >> 6, l = rem & 63;
    int lr = l & 15, lg = l >> 4;
    int n = cb * 16 + lr, k0 = kk * 32 + lg * 8;
    short pk[8];
    if (!tr) {
#pragma unroll
        for (int e = 0; e < 8; ++e) pk[e] = f2bf(W[(size_t)(k0 + e) * N + n]);
    } else {
#pragma unroll
        for (int e = 0; e < 8; ++e) pk[e] = f2bf(W[(size_t)n * 256 + (k0 + e)]);
    }
    *reinterpret_cast<bf16x8*>(P + (size_t)ci * 8) = *reinterpret_cast<bf16x8*>(pk);
}

// ---------------- K2: LN1 + Q-proj + z = per-head Wk^T q (MFMA) ------------
__global__ void ln1z(const float* __restrict__ tq, const short* __restrict__ WqP,
                     const float* __restrict__ bq, const float* __restrict__ g1,
                     const float* __restrict__ be1, const short* __restrict__ WkP,
                     const float* __restrict__ bk, short* __restrict__ zf,
                     float* __restrict__ sbg) {
    __shared__ float xs[8 * 260];
    __shared__ float qs[8 * 260];
    __shared__ short zst[8 * 2048];   // zf-layout staging for coalesced stores
    int r0 = blockIdx.x * 8, t = threadIdx.x;
    int w = t >> 6, l = t & 63, lr = l & 15, lg = l >> 4;
#pragma unroll
    for (int it = 0; it < 8; ++it) xs[it * 260 + t] = tq[(size_t)(r0 + it) * 256 + t];
    __syncthreads();
#pragma unroll
    for (int i = 0; i < 2; ++i) {
        int r = w * 2 + i;
        float s = 0.f, s2 = 0.f;
        for (int j = l; j < 256; j += 64) { float x = xs[r * 260 + j]; s += x; s2 += x * x; }
#pragma unroll
        for (int m = 1; m < 64; m <<= 1) { s += __shfl_xor(s, m); s2 += __shfl_xor(s2, m); }
        float mu = s * (1.f / 256.f);
        float var = s2 * (1.f / 256.f) - mu * mu;
        float rstd = rsqrtf(var + 1e-5f);
        for (int j = l; j < 256; j += 64)
            xs[r * 260 + j] = (xs[r * 260 + j] - mu) * rstd * g1[j] + be1[j];
    }
    __syncthreads();
    f32x4 cq[4];
#pragma unroll
    for (int ni = 0; ni < 4; ++ni) cq[ni] = (f32x4){0.f, 0.f, 0.f, 0.f};
#pragma unroll
    for (int kk = 0; kk < 8; ++kk) {
        bf16x8 af = {0, 0, 0, 0, 0, 0, 0, 0};
        if (lr < 8) {
            const float* xp = &xs[lr * 260 + kk * 32 + lg * 8];
            af = pack8(xp[0], xp[1], xp[2], xp[3], xp[4], xp[5], xp[6], xp[7]);
        }
#pragma unroll
        for (int ni = 0; ni < 4; ++ni) {
            bf16x8 bf = *reinterpret_cast<const bf16x8*>(WqP + ((size_t)((w * 4 + ni) * 8 + kk) * 64 + l) * 8);
            cq[ni] = __builtin_amdgcn_mfma_f32_16x16x32_bf16(af, bf, cq[ni], 0, 0, 0);
        }
    }
    if (lg < 2) {
#pragma unroll
        for (int ni = 0; ni < 4; ++ni)
#pragma unroll
            for (int r = 0; r < 4; ++r) {
                int row = lg * 4 + r, col = (w * 4 + ni) * 16 + lr;
                qs[row * 260 + col] = cq[ni][r] + bq[col];
            }
    }
    __syncthreads();
    if (t < 64) {
        int r = t >> 3, h = t & 7;
        float s = 0.f;
        for (int d = 0; d < 32; ++d) s += qs[r * 260 + h * 32 + d] * bk[h * 32 + d];
        sbg[(size_t)(r0 + r) * 8 + h] = s;
    }
    f32x4 cz[4][4];
#pragma unroll
    for (int mi = 0; mi < 4; ++mi)
#pragma unroll
        for (int ni = 0; ni < 4; ++ni) cz[mi][ni] = (f32x4){0.f, 0.f, 0.f, 0.f};
#pragma unroll
    for (int kk = 0; kk < 8; ++kk) {
        bf16x8 am[4];
#pragma unroll
        for (int mi = 0; mi < 4; ++mi) {
            bf16x8 z = {0, 0, 0, 0, 0, 0, 0, 0};
            if ((lr & 7) == kk) {
                int rr = mi * 2 + (lr >> 3);
                const float* qp = &qs[rr * 260 + kk * 32 + lg * 8];
                z = pack8(qp[0], qp[1], qp[2], qp[3], qp[4], qp[5], qp[6], qp[7]);
            }
            am[mi] = z;
        }
#pragma unroll
        for (int ni = 0; ni < 4; ++ni) {
            bf16x8 bf = *reinterpret_cast<const bf16x8*>(WkP + ((size_t)((w * 4 + ni) * 8 + kk) * 64 + l) * 8);
#pragma unroll
            for (int mi = 0; mi < 4; ++mi)
                cz[mi][ni] = __builtin_amdgcn_mfma_f32_16x16x32_bf16(am[mi], bf, cz[mi][ni], 0, 0, 0);
        }
    }
    // stage z in zf layout in LDS, then coalesced b128 stores
#pragma unroll
    for (int mi = 0; mi < 4; ++mi)
#pragma unroll
        for (int ni = 0; ni < 4; ++ni)
#pragma unroll
            for (int r = 0; r < 4; ++r) {
                int mrow = mi * 16 + lg * 4 + r;
                int rr = mrow >> 3, hh = mrow & 7;
                int i = (w * 4 + ni) * 16 + lr;
                zst[rr * 2048 + (i >> 3) * 64 + hh * 8 + (i & 7)] = f2bf(cz[mi][ni][r]);
            }
    __syncthreads();
#pragma unroll
    for (int it = 0; it < 8; ++it) {
        int c = it * 256 + t;
        *reinterpret_cast<bf16x8*>(zf + (size_t)r0 * 2048 + (size_t)c * 8) =
            *reinterpret_cast<const bf16x8*>(&zst[c * 8]);
    }
}

// ---------------- K3: attention per bq, X staged once in LDS ---------------
// LDS arena: Xs 32768B (bf16 [64][256], swizzle byte^=((key&7)<<4))
//            sp  2176B (float [8][68]: scores then P in-place)
//            us  4096B (bf16 [8][256], swizzle byte^=((h&7)<<4))
__launch_bounds__(256, 4)
__global__ void attn(const float* __restrict__ sf, const short* __restrict__ zf,
                     const float* __restrict__ sbg, const short* __restrict__ WvP,
                     const float* __restrict__ bv, short* __restrict__ aob,
                     float* __restrict__ attn_w) {
    __shared__ __align__(16) char arena[39040];
    char* Xb = arena;
    float* sp = reinterpret_cast<float*>(arena + 32768);
    char* Ub = arena + 34944;

    int bq = blockIdx.x, t = threadIdx.x;
    int w = t >> 6, l = t & 63, lr = l & 15, lg = l >> 4;
    const float* Xg = sf + (size_t)bq * 16384;

    // issue all 16 X loads
    float4 fa[16];
#pragma unroll
    for (int q = 0; q < 8; ++q) {
        int c = q * 256 + t;
        fa[2 * q]     = *reinterpret_cast<const float4*>(Xg + c * 8);
        fa[2 * q + 1] = *reinterpret_cast<const float4*>(Xg + c * 8 + 4);
    }
    // issue z A-frag loads (overlap with X loads in flight)
    bf16x8 zfr[8];
#pragma unroll
    for (int kk = 0; kk < 8; ++kk) {
        bf16x8 z = {0, 0, 0, 0, 0, 0, 0, 0};
        if (lr < 8)
            z = *reinterpret_cast<const bf16x8*>(zf + (size_t)bq * 2048 + ((size_t)((kk * 4 + lg) * 8 + lr)) * 8);
        zfr[kk] = z;
    }
    // convert + write LDS
#pragma unroll
    for (int q = 0; q < 8; ++q) {
        int c = q * 256 + t;
        int key = c >> 5, ch = (c & 31) * 8;
        int base = (key * 512 + ch * 2) ^ ((key & 7) << 4);
        *reinterpret_cast<bf16x8*>(Xb + base) =
            pack8(fa[2 * q].x, fa[2 * q].y, fa[2 * q].z, fa[2 * q].w,
                  fa[2 * q + 1].x, fa[2 * q + 1].y, fa[2 * q + 1].z, fa[2 * q + 1].w);
    }
    __syncthreads();

    // Phase 1: S^T = z^T @ X^T ; wave w covers keys w*16..+15
    f32x4 cs = {0.f, 0.f, 0.f, 0.f};
    {
        int key = w * 16 + lr;
        int swz = (key & 7) << 4;
#pragma unroll
        for (int kk = 0; kk < 8; ++kk) {
            int addr = (key * 512 + kk * 64 + lg * 16) ^ swz;
            bf16x8 xb = *reinterpret_cast<const bf16x8*>(Xb + addr);
            cs = __builtin_amdgcn_mfma_f32_16x16x32_bf16(zfr[kk], xb, cs, 0, 0, 0);
        }
    }
    if (lg < 2) {
#pragma unroll
        for (int r = 0; r < 4; ++r)
            sp[(lg * 4 + r) * 68 + w * 16 + lr] = cs[r];
    }
    __syncthreads();

    // Phase 2: softmax (in-place in sp) — wave w: heads 2w,2w+1; lane = key
    // sp rows 2w,2w+1 are written and then read only by wave w -> no barrier after
    const float scale = 0.17677669529663687f;  // 1/sqrt(32)
    int b = bq >> 11, qq = bq & 2047;
#pragma unroll
    for (int hi = 0; hi < 2; ++hi) {
        int h = w * 2 + hi;
        float sbh = sbg[(size_t)bq * 8 + h];
        float s = (sp[h * 68 + l] + sbh) * scale;
        float m = s;
#pragma unroll
        for (int off = 1; off < 64; off <<= 1) m = fmaxf(m, __shfl_xor(m, off));
        float p = __expf(s - m);
        float sm = p;
#pragma unroll
        for (int off = 1; off < 64; off <<= 1) sm += __shfl_xor(sm, off);
        float P = p / sm;
        sp[h * 68 + l] = P;
        attn_w[(((size_t)b * 8 + h) * QTOT + qq) * 64 + l] = P;
    }

    // Phase 3: u = P @ X on VALU; thread owns (h = t>>5, cg = t&31)
    // h = 2w or 2w+1 for threads of wave w -> reads only wave-local sp rows
    {
        int h = t >> 5, cg = t & 31;
        float acc[8];
#pragma unroll
        for (int e = 0; e < 8; ++e) acc[e] = 0.f;
#pragma unroll
        for (int k4 = 0; k4 < 16; ++k4) {
            float4 pv = *reinterpret_cast<const float4*>(&sp[h * 68 + k4 * 4]);
#pragma unroll
            for (int e = 0; e < 4; ++e) {
                int key = k4 * 4 + e;
                float P = (e == 0) ? pv.x : (e == 1) ? pv.y : (e == 2) ? pv.z : pv.w;
                int addr = (key * 512 + cg * 16) ^ ((key & 7) << 4);
                union { bf16x8 v; unsigned u[4]; } xv;
                xv.v = *reinterpret_cast<const bf16x8*>(Xb + addr);
#pragma unroll
                for (int d = 0; d < 4; ++d) {
                    union { unsigned u; float f; } lo, hi;
                    lo.u = xv.u[d] << 16;
                    hi.u = xv.u[d] & 0xffff0000u;
                    acc[2 * d]     += P * lo.f;
                    acc[2 * d + 1] += P * hi.f;
                }
            }
        }
        int ub = (h * 512 + cg * 16) ^ ((h & 7) << 4);
        *reinterpret_cast<bf16x8*>(Ub + ub) =
            pack8(acc[0], acc[1], acc[2], acc[3], acc[4], acc[5], acc[6], acc[7]);
    }
    __syncthreads();

    // Phase 4: out = u @ Wv (M=16, rows 0-7 valid); wave w covers cols w*64..+63
    f32x4 co[4];
#pragma unroll
    for (int ni = 0; ni < 4; ++ni) co[ni] = (f32x4){0.f, 0.f, 0.f, 0.f};
#pragma unroll
    for (int kk = 0; kk < 8; ++kk) {
        bf16x8 ua = {0, 0, 0, 0, 0, 0, 0, 0};
        if (lr < 8) {
            int addr = (lr * 512 + kk * 64 + lg * 16) ^ ((lr & 7) << 4);
            ua = *reinterpret_cast<const bf16x8*>(Ub + addr);
        }
#pragma unroll
        for (int ni = 0; ni < 4; ++ni) {
            bf16x8 bf = *reinterpret_cast<const bf16x8*>(WvP + ((size_t)((w * 4 + ni) * 8 + kk) * 64 + l) * 8);
            co[ni] = __builtin_amdgcn_mfma_f32_16x16x32_bf16(ua, bf, co[ni], 0, 0, 0);
        }
    }
    if (lg < 2) {
#pragma unroll
        for (int ni = 0; ni < 4; ++ni) {
            int j = (w * 4 + ni) * 16 + lr;
            int h = j >> 5;
            if ((h >> 2) == lg)
                aob[(size_t)bq * 256 + j] = f2bf(co[ni][h & 3] + bv[j]);
        }
    }
}

// ---------------- K4: fused tail (512 thr, 16 rows): oproj+LN2+FFN+res -----
__launch_bounds__(512, 1)
__global__ void tail(const short* __restrict__ aob, const float* __restrict__ tq,
                     const short* __restrict__ WoP, const float* __restrict__ bo,
                     const float* __restrict__ g2, const float* __restrict__ be2,
                     const short* __restrict__ W1P, const float* __restrict__ b1,
                     const short* __restrict__ W2P, const float* __restrict__ b2,
                     float* __restrict__ out) {
    __shared__ float xrow[16][260];
    __shared__ short xn[16][264];
    __shared__ short hs[16][1048];
    int r0 = blockIdx.x * 16, t = threadIdx.x;
    int w = t >> 6, l = t & 63, lr = l & 15, lg = l >> 4;

    // Phase A: oproj, wave w covers cols w*32..+31 (2 n-tiles)
    f32x4 c[2];
#pragma unroll
    for (int ni = 0; ni < 2; ++ni) c[ni] = (f32x4){0.f, 0.f, 0.f, 0.f};
#pragma unroll
    for (int kk = 0; kk < 8; ++kk) {
        bf16x8 af = *reinterpret_cast<const bf16x8*>(aob + (size_t)(r0 + lr) * 256 + kk * 32 + lg * 8);
#pragma unroll
        for (int ni = 0; ni < 2; ++ni) {
            bf16x8 bf = *reinterpret_cast<const bf16x8*>(WoP + ((size_t)((w * 2 + ni) * 8 + kk) * 64 + l) * 8);
            c[ni] = __builtin_amdgcn_mfma_f32_16x16x32_bf16(af, bf, c[ni], 0, 0, 0);
        }
    }
#pragma unroll
    for (int ni = 0; ni < 2; ++ni) {
        int col = (w * 2 + ni) * 16 + lr;
        float bb = bo[col];
#pragma unroll
        for (int r = 0; r < 4; ++r) {
            int row = lg * 4 + r;
            xrow[row][col] = tq[(size_t)(r0 + row) * 256 + col] + c[ni][r] + bb;
        }
    }
    __syncthreads();

    // Phase B: LN2 -> xn (bf16), 2 rows per wave
#pragma unroll
    for (int i = 0; i < 2; ++i) {
        int r = w * 2 + i;
        float s = 0.f, s2 = 0.f;
        for (int j = l; j < 256; j += 64) { float x = xrow[r][j]; s += x; s2 += x * x; }
#pragma unroll
        for (int m = 1; m < 64; m <<= 1) { s += __shfl_xor(s, m); s2 += __shfl_xor(s2, m); }
        float mu = s * (1.f / 256.f);
        float var = s2 * (1.f / 256.f) - mu * mu;
        float rstd = rsqrtf(var + 1e-5f);
        for (int j = l; j < 256; j += 64)
            xn[r][j] = f2bf((xrow[r][j] - mu) * rstd * g2[j] + be2[j]);
    }
    __syncthreads();

    // Phase C: FFN1 + GELU -> hs, wave covers cols w*128..+127 (8 n-tiles)
    bf16x8 af1[8];
#pragma unroll
    for (int kk = 0; kk < 8; ++kk)
        af1[kk] = *reinterpret_cast<const bf16x8*>(&xn[lr][kk * 32 + lg * 8]);
#pragma unroll
    for (int nt = 0; nt < 8; ++nt) {
        int cb = w * 8 + nt;
        f32x4 cc = {0.f, 0.f, 0.f, 0.f};
#pragma unroll
        for (int kk = 0; kk < 8; ++kk) {
            bf16x8 bf = *reinterpret_cast<const bf16x8*>(W1P + ((size_t)(cb * 8 + kk) * 64 + l) * 8);
            cc = __builtin_amdgcn_mfma_f32_16x16x32_bf16(af1[kk], bf, cc, 0, 0, 0);
        }
        int col = cb * 16 + lr;
        float bb = b1[col];
#pragma unroll
        for (int r = 0; r < 4; ++r) {
            int row = lg * 4 + r;
            float v = cc[r] + bb;
            float g = 0.5f * v * (1.f + erff(v * 0.7071067811865475f));
            hs[row][col] = f2bf(g);
        }
    }
    __syncthreads();

    // Phase D: FFN2 + residual, wave covers cols w*32..+31 (2 n-tiles, K=1024)
    f32x4 c2[2];
#pragma unroll
    for (int ni = 0; ni < 2; ++ni) c2[ni] = (f32x4){0.f, 0.f, 0.f, 0.f};
#pragma unroll
    for (int kk = 0; kk < 32; ++kk) {
        bf16x8 af = *reinterpret_cast<const bf16x8*>(&hs[lr][kk * 32 + lg * 8]);
#pragma unroll
        for (int ni = 0; ni < 2; ++ni) {
            bf16x8 bf = *reinterpret_cast<const bf16x8*>(W2P + ((size_t)((w * 2 + ni) * 32 + kk) * 64 + l) * 8);
            c2[ni] = __builtin_amdgcn_mfma_f32_16x16x32_bf16(af, bf, c2[ni], 0, 0, 0);
        }
    }
#pragma unroll
    for (int ni = 0; ni < 2; ++ni) {
        int col = (w * 2 + ni) * 16 + lr;
        float bb = b2[col];
#pragma unroll
        for (int r = 0; r < 4; ++r) {
            int row = lg * 4 + r;
            out[(size_t)(r0 + row) * 256 + col] = xrow[row][col] + c2[ni][r] + bb;
        }
    }
}

extern "C" void kernel_launch(void* const* d_in, const int* in_sizes, int n_in,
                              void* d_out, int out_size, void* d_ws, size_t ws_size,
                              hipStream_t stream) {
    const float* tq  = (const float*)d_in[0];
    const float* sf  = (const float*)d_in[1];
    const float* Wq  = (const float*)d_in[2];
    const float* bq  = (const float*)d_in[3];
    const float* Wk  = (const float*)d_in[4];
    const float* bk  = (const float*)d_in[5];
    const float* Wv  = (const float*)d_in[6];
    const float* bv  = (const float*)d_in[7];
    const float* Wo  = (const float*)d_in[8];
    const float* bo  = (const float*)d_in[9];
    const float* g1  = (const float*)d_in[10];
    const float* be1 = (const float*)d_in[11];
    const float* g2  = (const float*)d_in[12];
    const float* be2 = (const float*)d_in[13];
    const float* W1  = (const float*)d_in[14];
    const float* b1  = (const float*)d_in[15];
    const float* W2  = (const float*)d_in[16];
    const float* b2  = (const float*)d_in[17];

    char* wsb = (char*)d_ws;
    short* WqP = (short*)(wsb + 0);         // 128KB
    short* WkP = (short*)(wsb + 131072);    // 128KB (transposed pack)
    short* WoP = (short*)(wsb + 262144);    // 128KB
    short* WvP = (short*)(wsb + 393216);    // 128KB
    short* W1P = (short*)(wsb + 524288);    // 512KB
    short* W2P = (short*)(wsb + 1048576);   // 512KB
    float* sbw = (float*)(wsb + 1572864);   // 128KB
    short* zf  = (short*)(wsb + 1703936);   // 16MB
    short* aob = (short*)(wsb + 18481152);  // 2MB bf16

    float* outp   = (float*)d_out;
    float* attnwp = (float*)d_out + 1048576;

    wconv<<<384, 256, 0, stream>>>(Wq, Wk, Wo, Wv, W1, W2, WqP, WkP, WoP, WvP, W1P, W2P);
    ln1z<<<512, 256, 0, stream>>>(tq, WqP, bq, g1, be1, WkP, bk, zf, sbw);
    attn<<<4096, 256, 0, stream>>>(sf, zf, sbw, WvP, bv, aob, attnwp);
    tail<<<256, 512, 0, stream>>>(aob, tq, WoP, bo, g2, be2, W1P, b1, W2P, b2, outp);
}

// Round 13
// 130.251 us; speedup vs baseline: 1.1123x; 1.1123x over previous
//
#include <hip/hip_runtime.h>
#include <math.h>

#define QTOT 2048

using bf16x8 = __attribute__((ext_vector_type(8))) short;
using f32x4  = __attribute__((ext_vector_type(4))) float;

static __device__ __forceinline__ short f2bf(float f) {
    union { float f; unsigned u; } v; v.f = f;
    unsigned r = v.u + 0x7fffu + ((v.u >> 16) & 1u);
    return (short)(r >> 16);
}
static __device__ __forceinline__ unsigned cvt_pk(float a, float b) {
    unsigned r;
    asm("v_cvt_pk_bf16_f32 %0, %1, %2" : "=v"(r) : "v"(a), "v"(b));
    return r;
}
static __device__ __forceinline__ bf16x8 pack8(float a0, float a1, float a2, float a3,
                                               float a4, float a5, float a6, float a7) {
    union { unsigned u[4]; bf16x8 v; } z;
    z.u[0] = cvt_pk(a0, a1); z.u[1] = cvt_pk(a2, a3);
    z.u[2] = cvt_pk(a4, a5); z.u[3] = cvt_pk(a6, a7);
    return z.v;
}

// ---------------- K1: pack all weights into MFMA B-fragment order ----------
__global__ void wconv(const float* __restrict__ Wq, const float* __restrict__ Wk,
                      const float* __restrict__ Wo, const float* __restrict__ Wv,
                      const float* __restrict__ W1, const float* __restrict__ W2,
                      short* __restrict__ WqP, short* __restrict__ WkP,
                      short* __restrict__ WoP, short* __restrict__ WvP,
                      short* __restrict__ W1P, short* __restrict__ W2P) {
    int b = blockIdx.x, t = threadIdx.x;
    const float* W; short* P; int N, KK, ci; bool tr = false;
    if (b < 32)       { W = Wq; P = WqP; N = 256;  KK = 8;  ci = b * 256 + t; }
    else if (b < 64)  { W = Wk; P = WkP; N = 256;  KK = 8;  ci = (b - 32) * 256 + t; tr = true; }
    else if (b < 96)  { W = Wo; P = WoP; N = 256;  KK = 8;  ci = (b - 64) * 256 + t; }
    else if (b < 128) { W = Wv; P = WvP; N = 256;  KK = 8;  ci = (b - 96) * 256 + t; }
    else if (b < 256) { W = W1; P = W1P; N = 1024; KK = 8;  ci = (b - 128) * 256 + t; }
    else              { W = W2; P = W2P; N = 256;  KK = 32; ci = (b - 256) * 256 + t; }
    int cb = ci / (KK * 64);
    int rem = ci - cb * (KK * 64);
    int kk = rem >> 6, l = rem & 63;
    int lr = l & 15, lg = l >> 4;
    int n = cb * 16 + lr, k0 = kk * 32 + lg * 8;
    short pk[8];
    if (!tr) {
#pragma unroll
        for (int e = 0; e < 8; ++e) pk[e] = f2bf(W[(size_t)(k0 + e) * N + n]);
    } else {
#pragma unroll
        for (int e = 0; e < 8; ++e) pk[e] = f2bf(W[(size_t)n * 256 + (k0 + e)]);
    }
    *reinterpret_cast<bf16x8*>(P + (size_t)ci * 8) = *reinterpret_cast<bf16x8*>(pk);
}

// ---------------- K2: LN1 + Q-proj + z = per-head Wk^T q (MFMA) ------------
__global__ void ln1z(const float* __restrict__ tq, const short* __restrict__ WqP,
                     const float* __restrict__ bq, const float* __restrict__ g1,
                     const float* __restrict__ be1, const short* __restrict__ WkP,
                     const float* __restrict__ bk, short* __restrict__ zf,
                     float* __restrict__ sbg) {
    __shared__ float xs[8 * 260];
    __shared__ float qs[8 * 260];
    __shared__ short zst[8 * 2048];   // zf-layout staging for coalesced stores
    int r0 = blockIdx.x * 8, t = threadIdx.x;
    int w = t >> 6, l = t & 63, lr = l & 15, lg = l >> 4;
#pragma unroll
    for (int it = 0; it < 8; ++it) xs[it * 260 + t] = tq[(size_t)(r0 + it) * 256 + t];
    __syncthreads();
#pragma unroll
    for (int i = 0; i < 2; ++i) {
        int r = w * 2 + i;
        float s = 0.f, s2 = 0.f;
        for (int j = l; j < 256; j += 64) { float x = xs[r * 260 + j]; s += x; s2 += x * x; }
#pragma unroll
        for (int m = 1; m < 64; m <<= 1) { s += __shfl_xor(s, m); s2 += __shfl_xor(s2, m); }
        float mu = s * (1.f / 256.f);
        float var = s2 * (1.f / 256.f) - mu * mu;
        float rstd = rsqrtf(var + 1e-5f);
        for (int j = l; j < 256; j += 64)
            xs[r * 260 + j] = (xs[r * 260 + j] - mu) * rstd * g1[j] + be1[j];
    }
    __syncthreads();
    f32x4 cq[4];
#pragma unroll
    for (int ni = 0; ni < 4; ++ni) cq[ni] = (f32x4){0.f, 0.f, 0.f, 0.f};
#pragma unroll
    for (int kk = 0; kk < 8; ++kk) {
        bf16x8 af = {0, 0, 0, 0, 0, 0, 0, 0};
        if (lr < 8) {
            const float* xp = &xs[lr * 260 + kk * 32 + lg * 8];
            af = pack8(xp[0], xp[1], xp[2], xp[3], xp[4], xp[5], xp[6], xp[7]);
        }
#pragma unroll
        for (int ni = 0; ni < 4; ++ni) {
            bf16x8 bf = *reinterpret_cast<const bf16x8*>(WqP + ((size_t)((w * 4 + ni) * 8 + kk) * 64 + l) * 8);
            cq[ni] = __builtin_amdgcn_mfma_f32_16x16x32_bf16(af, bf, cq[ni], 0, 0, 0);
        }
    }
    if (lg < 2) {
#pragma unroll
        for (int ni = 0; ni < 4; ++ni)
#pragma unroll
            for (int r = 0; r < 4; ++r) {
                int row = lg * 4 + r, col = (w * 4 + ni) * 16 + lr;
                qs[row * 260 + col] = cq[ni][r] + bq[col];
            }
    }
    __syncthreads();
    if (t < 64) {
        int r = t >> 3, h = t & 7;
        float s = 0.f;
        for (int d = 0; d < 32; ++d) s += qs[r * 260 + h * 32 + d] * bk[h * 32 + d];
        sbg[(size_t)(r0 + r) * 8 + h] = s;
    }
    f32x4 cz[4][4];
#pragma unroll
    for (int mi = 0; mi < 4; ++mi)
#pragma unroll
        for (int ni = 0; ni < 4; ++ni) cz[mi][ni] = (f32x4){0.f, 0.f, 0.f, 0.f};
#pragma unroll
    for (int kk = 0; kk < 8; ++kk) {
        bf16x8 am[4];
#pragma unroll
        for (int mi = 0; mi < 4; ++mi) {
            bf16x8 z = {0, 0, 0, 0, 0, 0, 0, 0};
            if ((lr & 7) == kk) {
                int rr = mi * 2 + (lr >> 3);
                const float* qp = &qs[rr * 260 + kk * 32 + lg * 8];
                z = pack8(qp[0], qp[1], qp[2], qp[3], qp[4], qp[5], qp[6], qp[7]);
            }
            am[mi] = z;
        }
#pragma unroll
        for (int ni = 0; ni < 4; ++ni) {
            bf16x8 bf = *reinterpret_cast<const bf16x8*>(WkP + ((size_t)((w * 4 + ni) * 8 + kk) * 64 + l) * 8);
#pragma unroll
            for (int mi = 0; mi < 4; ++mi)
                cz[mi][ni] = __builtin_amdgcn_mfma_f32_16x16x32_bf16(am[mi], bf, cz[mi][ni], 0, 0, 0);
        }
    }
    // stage z in zf layout in LDS, then coalesced b128 stores
#pragma unroll
    for (int mi = 0; mi < 4; ++mi)
#pragma unroll
        for (int ni = 0; ni < 4; ++ni)
#pragma unroll
            for (int r = 0; r < 4; ++r) {
                int mrow = mi * 16 + lg * 4 + r;
                int rr = mrow >> 3, hh = mrow & 7;
                int i = (w * 4 + ni) * 16 + lr;
                zst[rr * 2048 + (i >> 3) * 64 + hh * 8 + (i & 7)] = f2bf(cz[mi][ni][r]);
            }
    __syncthreads();
#pragma unroll
    for (int it = 0; it < 8; ++it) {
        int c = it * 256 + t;
        *reinterpret_cast<bf16x8*>(zf + (size_t)r0 * 2048 + (size_t)c * 8) =
            *reinterpret_cast<const bf16x8*>(&zst[c * 8]);
    }
}

// ---------------- K3: attention per bq, X staged once in LDS ---------------
// LDS arena: Xs 32768B (bf16 [64][256], swizzle byte^=((key&7)<<4))
//            sp  2176B (float [8][68]: scores then P in-place)
//            us  4096B (bf16 [8][256], swizzle byte^=((h&7)<<4))
__launch_bounds__(256, 4)
__global__ void attn(const float* __restrict__ sf, const short* __restrict__ zf,
                     const float* __restrict__ sbg, const short* __restrict__ WvP,
                     const float* __restrict__ bv, short* __restrict__ aob,
                     float* __restrict__ attn_w) {
    __shared__ __align__(16) char arena[39040];
    char* Xb = arena;
    float* sp = reinterpret_cast<float*>(arena + 32768);
    char* Ub = arena + 34944;

    int bq = blockIdx.x, t = threadIdx.x;
    int w = t >> 6, l = t & 63, lr = l & 15, lg = l >> 4;
    const float* Xg = sf + (size_t)bq * 16384;

    // issue all 16 X loads
    float4 fa[16];
#pragma unroll
    for (int q = 0; q < 8; ++q) {
        int c = q * 256 + t;
        fa[2 * q]     = *reinterpret_cast<const float4*>(Xg + c * 8);
        fa[2 * q + 1] = *reinterpret_cast<const float4*>(Xg + c * 8 + 4);
    }
    // issue z A-frag loads (overlap with X loads in flight)
    bf16x8 zfr[8];
#pragma unroll
    for (int kk = 0; kk < 8; ++kk) {
        bf16x8 z = {0, 0, 0, 0, 0, 0, 0, 0};
        if (lr < 8)
            z = *reinterpret_cast<const bf16x8*>(zf + (size_t)bq * 2048 + ((size_t)((kk * 4 + lg) * 8 + lr)) * 8);
        zfr[kk] = z;
    }
    // convert + write LDS
#pragma unroll
    for (int q = 0; q < 8; ++q) {
        int c = q * 256 + t;
        int key = c >> 5, ch = (c & 31) * 8;
        int base = (key * 512 + ch * 2) ^ ((key & 7) << 4);
        *reinterpret_cast<bf16x8*>(Xb + base) =
            pack8(fa[2 * q].x, fa[2 * q].y, fa[2 * q].z, fa[2 * q].w,
                  fa[2 * q + 1].x, fa[2 * q + 1].y, fa[2 * q + 1].z, fa[2 * q + 1].w);
    }
    __syncthreads();

    // Phase 1: S^T = z^T @ X^T ; wave w covers keys w*16..+15
    f32x4 cs = {0.f, 0.f, 0.f, 0.f};
    {
        int key = w * 16 + lr;
        int swz = (key & 7) << 4;
#pragma unroll
        for (int kk = 0; kk < 8; ++kk) {
            int addr = (key * 512 + kk * 64 + lg * 16) ^ swz;
            bf16x8 xb = *reinterpret_cast<const bf16x8*>(Xb + addr);
            cs = __builtin_amdgcn_mfma_f32_16x16x32_bf16(zfr[kk], xb, cs, 0, 0, 0);
        }
    }
    if (lg < 2) {
#pragma unroll
        for (int r = 0; r < 4; ++r)
            sp[(lg * 4 + r) * 68 + w * 16 + lr] = cs[r];
    }
    __syncthreads();

    // Phase 2: softmax (in-place in sp) — wave w: heads 2w,2w+1; lane = key
    const float scale = 0.17677669529663687f;  // 1/sqrt(32)
    int b = bq >> 11, qq = bq & 2047;
#pragma unroll
    for (int hi = 0; hi < 2; ++hi) {
        int h = w * 2 + hi;
        float sbh = sbg[(size_t)bq * 8 + h];
        float s = (sp[h * 68 + l] + sbh) * scale;
        float m = s;
#pragma unroll
        for (int off = 1; off < 64; off <<= 1) m = fmaxf(m, __shfl_xor(m, off));
        float p = __expf(s - m);
        float sm = p;
#pragma unroll
        for (int off = 1; off < 64; off <<= 1) sm += __shfl_xor(sm, off);
        float P = p / sm;
        sp[h * 68 + l] = P;
        attn_w[(((size_t)b * 8 + h) * QTOT + qq) * 64 + l] = P;
    }
    __syncthreads();

    // Phase 3: u = P @ X on VALU; thread owns (h = t>>5, cg = t&31)
    {
        int h = t >> 5, cg = t & 31;
        float acc[8];
#pragma unroll
        for (int e = 0; e < 8; ++e) acc[e] = 0.f;
#pragma unroll
        for (int k4 = 0; k4 < 16; ++k4) {
            float4 pv = *reinterpret_cast<const float4*>(&sp[h * 68 + k4 * 4]);
#pragma unroll
            for (int e = 0; e < 4; ++e) {
                int key = k4 * 4 + e;
                float P = (e == 0) ? pv.x : (e == 1) ? pv.y : (e == 2) ? pv.z : pv.w;
                int addr = (key * 512 + cg * 16) ^ ((key & 7) << 4);
                union { bf16x8 v; unsigned u[4]; } xv;
                xv.v = *reinterpret_cast<const bf16x8*>(Xb + addr);
#pragma unroll
                for (int d = 0; d < 4; ++d) {
                    union { unsigned u; float f; } lo, hi;
                    lo.u = xv.u[d] << 16;
                    hi.u = xv.u[d] & 0xffff0000u;
                    acc[2 * d]     += P * lo.f;
                    acc[2 * d + 1] += P * hi.f;
                }
            }
        }
        int ub = (h * 512 + cg * 16) ^ ((h & 7) << 4);
        *reinterpret_cast<bf16x8*>(Ub + ub) =
            pack8(acc[0], acc[1], acc[2], acc[3], acc[4], acc[5], acc[6], acc[7]);
    }
    __syncthreads();

    // Phase 4: out = u @ Wv (M=16, rows 0-7 valid); wave w covers cols w*64..+63
    f32x4 co[4];
#pragma unroll
    for (int ni = 0; ni < 4; ++ni) co[ni] = (f32x4){0.f, 0.f, 0.f, 0.f};
#pragma unroll
    for (int kk = 0; kk < 8; ++kk) {
        bf16x8 ua = {0, 0, 0, 0, 0, 0, 0, 0};
        if (lr < 8) {
            int addr = (lr * 512 + kk * 64 + lg * 16) ^ ((lr & 7) << 4);
            ua = *reinterpret_cast<const bf16x8*>(Ub + addr);
        }
#pragma unroll
        for (int ni = 0; ni < 4; ++ni) {
            bf16x8 bf = *reinterpret_cast<const bf16x8*>(WvP + ((size_t)((w * 4 + ni) * 8 + kk) * 64 + l) * 8);
            co[ni] = __builtin_amdgcn_mfma_f32_16x16x32_bf16(ua, bf, co[ni], 0, 0, 0);
        }
    }
    if (lg < 2) {
#pragma unroll
        for (int ni = 0; ni < 4; ++ni) {
            int j = (w * 4 + ni) * 16 + lr;
            int h = j >> 5;
            if ((h >> 2) == lg)
                aob[(size_t)bq * 256 + j] = f2bf(co[ni][h & 3] + bv[j]);
        }
    }
}

// ---------------- K4: fused tail (512 thr, 16 rows): oproj+LN2+FFN+res -----
__launch_bounds__(512, 1)
__global__ void tail(const short* __restrict__ aob, const float* __restrict__ tq,
                     const short* __restrict__ WoP, const float* __restrict__ bo,
                     const float* __restrict__ g2, const float* __restrict__ be2,
                     const short* __restrict__ W1P, const float* __restrict__ b1,
                     const short* __restrict__ W2P, const float* __restrict__ b2,
                     float* __restrict__ out) {
    __shared__ float xrow[16][260];
    __shared__ short xn[16][264];
    __shared__ short hs[16][1048];
    int r0 = blockIdx.x * 16, t = threadIdx.x;
    int w = t >> 6, l = t & 63, lr = l & 15, lg = l >> 4;

    // Phase A: oproj, wave w covers cols w*32..+31 (2 n-tiles)
    f32x4 c[2];
#pragma unroll
    for (int ni = 0; ni < 2; ++ni) c[ni] = (f32x4){0.f, 0.f, 0.f, 0.f};
#pragma unroll
    for (int kk = 0; kk < 8; ++kk) {
        bf16x8 af = *reinterpret_cast<const bf16x8*>(aob + (size_t)(r0 + lr) * 256 + kk * 32 + lg * 8);
#pragma unroll
        for (int ni = 0; ni < 2; ++ni) {
            bf16x8 bf = *reinterpret_cast<const bf16x8*>(WoP + ((size_t)((w * 2 + ni) * 8 + kk) * 64 + l) * 8);
            c[ni] = __builtin_amdgcn_mfma_f32_16x16x32_bf16(af, bf, c[ni], 0, 0, 0);
        }
    }
#pragma unroll
    for (int ni = 0; ni < 2; ++ni) {
        int col = (w * 2 + ni) * 16 + lr;
        float bb = bo[col];
#pragma unroll
        for (int r = 0; r < 4; ++r) {
            int row = lg * 4 + r;
            xrow[row][col] = tq[(size_t)(r0 + row) * 256 + col] + c[ni][r] + bb;
        }
    }
    __syncthreads();

    // Phase B: LN2 -> xn (bf16), 2 rows per wave
#pragma unroll
    for (int i = 0; i < 2; ++i) {
        int r = w * 2 + i;
        float s = 0.f, s2 = 0.f;
        for (int j = l; j < 256; j += 64) { float x = xrow[r][j]; s += x; s2 += x * x; }
#pragma unroll
        for (int m = 1; m < 64; m <<= 1) { s += __shfl_xor(s, m); s2 += __shfl_xor(s2, m); }
        float mu = s * (1.f / 256.f);
        float var = s2 * (1.f / 256.f) - mu * mu;
        float rstd = rsqrtf(var + 1e-5f);
        for (int j = l; j < 256; j += 64)
            xn[r][j] = f2bf((xrow[r][j] - mu) * rstd * g2[j] + be2[j]);
    }
    __syncthreads();

    // Phase C: FFN1 + GELU -> hs, wave covers cols w*128..+127 (8 n-tiles)
    bf16x8 af1[8];
#pragma unroll
    for (int kk = 0; kk < 8; ++kk)
        af1[kk] = *reinterpret_cast<const bf16x8*>(&xn[lr][kk * 32 + lg * 8]);
#pragma unroll
    for (int nt = 0; nt < 8; ++nt) {
        int cb = w * 8 + nt;
        f32x4 cc = {0.f, 0.f, 0.f, 0.f};
#pragma unroll
        for (int kk = 0; kk < 8; ++kk) {
            bf16x8 bf = *reinterpret_cast<const bf16x8*>(W1P + ((size_t)(cb * 8 + kk) * 64 + l) * 8);
            cc = __builtin_amdgcn_mfma_f32_16x16x32_bf16(af1[kk], bf, cc, 0, 0, 0);
        }
        int col = cb * 16 + lr;
        float bb = b1[col];
#pragma unroll
        for (int r = 0; r < 4; ++r) {
            int row = lg * 4 + r;
            float v = cc[r] + bb;
            float g = 0.5f * v * (1.f + erff(v * 0.7071067811865475f));
            hs[row][col] = f2bf(g);
        }
    }
    __syncthreads();

    // Phase D: FFN2 + residual, wave covers cols w*32..+31 (2 n-tiles, K=1024)
    f32x4 c2[2];
#pragma unroll
    for (int ni = 0; ni < 2; ++ni) c2[ni] = (f32x4){0.f, 0.f, 0.f, 0.f};
#pragma unroll
    for (int kk = 0; kk < 32; ++kk) {
        bf16x8 af = *reinterpret_cast<const bf16x8*>(&hs[lr][kk * 32 + lg * 8]);
#pragma unroll
        for (int ni = 0; ni < 2; ++ni) {
            bf16x8 bf = *reinterpret_cast<const bf16x8*>(W2P + ((size_t)((w * 2 + ni) * 32 + kk) * 64 + l) * 8);
            c2[ni] = __builtin_amdgcn_mfma_f32_16x16x32_bf16(af, bf, c2[ni], 0, 0, 0);
        }
    }
#pragma unroll
    for (int ni = 0; ni < 2; ++ni) {
        int col = (w * 2 + ni) * 16 + lr;
        float bb = b2[col];
#pragma unroll
        for (int r = 0; r < 4; ++r) {
            int row = lg * 4 + r;
            out[(size_t)(r0 + row) * 256 + col] = xrow[row][col] + c2[ni][r] + bb;
        }
    }
}

extern "C" void kernel_launch(void* const* d_in, const int* in_sizes, int n_in,
                              void* d_out, int out_size, void* d_ws, size_t ws_size,
                              hipStream_t stream) {
    const float* tq  = (const float*)d_in[0];
    const float* sf  = (const float*)d_in[1];
    const float* Wq  = (const float*)d_in[2];
    const float* bq  = (const float*)d_in[3];
    const float* Wk  = (const float*)d_in[4];
    const float* bk  = (const float*)d_in[5];
    const float* Wv  = (const float*)d_in[6];
    const float* bv  = (const float*)d_in[7];
    const float* Wo  = (const float*)d_in[8];
    const float* bo  = (const float*)d_in[9];
    const float* g1  = (const float*)d_in[10];
    const float* be1 = (const float*)d_in[11];
    const float* g2  = (const float*)d_in[12];
    const float* be2 = (const float*)d_in[13];
    const float* W1  = (const float*)d_in[14];
    const float* b1  = (const float*)d_in[15];
    const float* W2  = (const float*)d_in[16];
    const float* b2  = (const float*)d_in[17];

    char* wsb = (char*)d_ws;
    short* WqP = (short*)(wsb + 0);         // 128KB
    short* WkP = (short*)(wsb + 131072);    // 128KB (transposed pack)
    short* WoP = (short*)(wsb + 262144);    // 128KB
    short* WvP = (short*)(wsb + 393216);    // 128KB
    short* W1P = (short*)(wsb + 524288);    // 512KB
    short* W2P = (short*)(wsb + 1048576);   // 512KB
    float* sbw = (float*)(wsb + 1572864);   // 128KB
    short* zf  = (short*)(wsb + 1703936);   // 16MB
    short* aob = (short*)(wsb + 18481152);  // 2MB bf16

    float* outp   = (float*)d_out;
    float* attnwp = (float*)d_out + 1048576;

    wconv<<<384, 256, 0, stream>>>(Wq, Wk, Wo, Wv, W1, W2, WqP, WkP, WoP, WvP, W1P, W2P);
    ln1z<<<512, 256, 0, stream>>>(tq, WqP, bq, g1, be1, WkP, bk, zf, sbw);
    attn<<<4096, 256, 0, stream>>>(sf, zf, sbw, WvP, bv, aob, attnwp);
    tail<<<256, 512, 0, stream>>>(aob, tq, WoP, bo, g2, be2, W1P, b1, W2P, b2, outp);
}